// Round 11
// baseline (32.074 us; speedup 1.0000x reference)
//
#include <hip/hip_runtime.h>

// Separable 3x3 window: w = outer(v,v), v = [A_W, B_W, A_W]
#define A_W 0.30780133f
#define B_W 0.38439735f

#define IMG_W 512
#define CROP_LO 5
#define CROP_HI 507          // exclusive; rows/cols 5..506 kept (502 each)
#define STRIP 16
#define NSTRIPS 32
#define BT 256

typedef float2 f2;

// Packed fp32 (VOP3P) — 2 cols per instruction. Non-volatile pure asm:
// scheduler may reorder by dependencies (good), cannot unpack (better).
#define PK_ADD(d, a, b)    asm("v_pk_add_f32 %0, %1, %2" : "=v"(d) : "v"(a), "v"(b))
#define PK_MUL(d, a, b)    asm("v_pk_mul_f32 %0, %1, %2" : "=v"(d) : "v"(a), "v"(b))
#define PK_FMA(d, a, b, c) asm("v_pk_fma_f32 %0, %1, %2, %3" : "=v"(d) : "v"(a), "v"(b), "v"(c))

struct HP { f2 a1, a2, a11, a22, a12; };   // h-sums for the 2 owned cols

// x covers cols [c0-1..c0+2]; windows: col c0 -> (x,y,z), col c0+1 -> (y,z,w)
__device__ __forceinline__ void hrow(const float4 x, const float4 y,
                                     const f2 A2, const f2 B2, HP& h) {
    f2 Lx = {x.x, x.y}, Mx = {x.y, x.z}, Rx = {x.z, x.w};
    f2 Ly = {y.x, y.y}, My = {y.y, y.z}, Ry = {y.z, y.w};
    f2 t, m, pL, pM, pR;
    PK_ADD(t, Lx, Rx); PK_MUL(m, B2, Mx); PK_FMA(h.a1, A2, t, m);
    PK_ADD(t, Ly, Ry); PK_MUL(m, B2, My); PK_FMA(h.a2, A2, t, m);
    PK_MUL(pL, Lx, Lx); PK_MUL(pM, Mx, Mx); PK_MUL(pR, Rx, Rx);
    PK_ADD(t, pL, pR); PK_MUL(m, B2, pM); PK_FMA(h.a11, A2, t, m);
    PK_MUL(pL, Ly, Ly); PK_MUL(pM, My, My); PK_MUL(pR, Ry, Ry);
    PK_ADD(t, pL, pR); PK_MUL(m, B2, pM); PK_FMA(h.a22, A2, t, m);
    PK_MUL(pL, Lx, Ly); PK_MUL(pM, Mx, My); PK_MUL(pR, Rx, Ry);
    PK_ADD(t, pL, pR); PK_MUL(m, B2, pM); PK_FMA(h.a12, A2, t, m);
}

__global__ __launch_bounds__(BT) void ssim_loss_main(
    const float* __restrict__ X, const float* __restrict__ Y,
    float* __restrict__ partials) {
    const int t  = threadIdx.x;
    const int c0 = 4 + 2 * t;              // owned cols c0, c0+1
    const int lc = min(c0, 508) - 1;       // float4 window base [lc..lc+3]
    const int b  = blockIdx.y;
    const int r0 = CROP_LO + STRIP * blockIdx.x;   // 5..501

    const float* Xb = X + (size_t)b * IMG_W * IMG_W;
    const float* Yb = Y + (size_t)b * IMG_W * IMG_W;

    const float cm0 = (c0     >= CROP_LO && c0     < CROP_HI) ? 1.0f : 0.0f;
    const float cm1 = (c0 + 1 >= CROP_LO && c0 + 1 < CROP_HI) ? 1.0f : 0.0f;
    const f2 A2 = {A_W, A_W}, B2 = {B_W, B_W};

    auto ld = [&](const float* base, int row) {
        return *(const float4*)(base + (size_t)min(row, IMG_W - 1) * IMG_W + lc);
    };

    HP P, C, N;
    hrow(ld(Xb, r0 - 1), ld(Yb, r0 - 1), A2, B2, P);
    hrow(ld(Xb, r0),     ld(Yb, r0),     A2, B2, C);

    float acc = 0.0f;
#pragma unroll
    for (int rr = 0; rr < STRIP; ++rr) {
        hrow(ld(Xb, r0 + rr + 1), ld(Yb, r0 + rr + 1), A2, B2, N);

        f2 s1, s2, s11, s22, s12, t2, m2;
        PK_ADD(t2, P.a1,  N.a1);  PK_MUL(m2, B2, C.a1);  PK_FMA(s1,  A2, t2, m2);
        PK_ADD(t2, P.a2,  N.a2);  PK_MUL(m2, B2, C.a2);  PK_FMA(s2,  A2, t2, m2);
        PK_ADD(t2, P.a11, N.a11); PK_MUL(m2, B2, C.a11); PK_FMA(s11, A2, t2, m2);
        PK_ADD(t2, P.a22, N.a22); PK_MUL(m2, B2, C.a22); PK_FMA(s22, A2, t2, m2);
        PK_ADD(t2, P.a12, N.a12); PK_MUL(m2, B2, C.a12); PK_FMA(s12, A2, t2, m2);

        // Final sigma-combine: scalar (small; compiler emits fma)
        float v1a = s11.x - s1.x * s1.x, v1b = s11.y - s1.y * s1.y;
        float v2a = s22.x - s2.x * s2.x, v2b = s22.y - s2.y * s2.y;
        float cva = s12.x - s1.x * s2.x, cvb = s12.y - s1.y * s2.y;
        float racc = cm0 * (v1a * v2a - 2.0f * cva)
                   + cm1 * (v1b * v2b - 2.0f * cvb);
        acc += (r0 + rr < CROP_HI) ? racc : 0.0f;   // row mask (tail strip)
        P = C; C = N;
    }

    // Block reduction: 4 waves.
    for (int off = 32; off > 0; off >>= 1) acc += __shfl_down(acc, off, 64);
    __shared__ float wsum[BT / 64];
    if ((t & 63) == 0) wsum[t >> 6] = acc;
    __syncthreads();
    if (t == 0)
        partials[blockIdx.x + NSTRIPS * b] = wsum[0] + wsum[1] + wsum[2] + wsum[3];
}

__global__ __launch_bounds__(256) void ssim_loss_finalize(
    const float* __restrict__ partials, int n, float* __restrict__ out) {
    const int tid = threadIdx.x;
    float s = 0.0f;
    for (int i = tid; i < n; i += 256) s += partials[i];
    for (int off = 32; off > 0; off >>= 1) s += __shfl_down(s, off, 64);
    __shared__ float wsum[4];
    if ((tid & 63) == 0) wsum[tid >> 6] = s;
    __syncthreads();
    if (tid == 0) {
        float total = wsum[0] + wsum[1] + wsum[2] + wsum[3];
        out[0] = total * (1.0f / 252004.0f);   // mean over 502*502, summed over batch
    }
}

extern "C" void kernel_launch(void* const* d_in, const int* in_sizes, int n_in,
                              void* d_out, int out_size, void* d_ws, size_t ws_size,
                              hipStream_t stream) {
    const float* X = (const float*)d_in[0];
    const float* Y = (const float*)d_in[1];
    float* out = (float*)d_out;
    float* partials = (float*)d_ws;   // NSTRIPS*64 = 2048 floats

    dim3 grid(NSTRIPS, 64);
    ssim_loss_main<<<grid, BT, 0, stream>>>(X, Y, partials);
    ssim_loss_finalize<<<1, 256, 0, stream>>>(partials, NSTRIPS * 64, out);
}